// Round 7
// baseline (648.668 us; speedup 1.0000x reference)
//
#include <hip/hip_runtime.h>
#include <stdint.h>

#define E_NUM 8
#define CAP 8192
#define NTOK 32768
#define CDIM 384
#define DFF 1536
#define CNT_PAD 64  // ints between counters -> 256B, separate cache lines

typedef unsigned short u16;
typedef __attribute__((ext_vector_type(8))) short short8;
typedef __attribute__((ext_vector_type(4))) float f32x4;

__device__ inline u16 f2bf(float f) {
    uint32_t u = __builtin_bit_cast(uint32_t, f);
    u += 0x7fffu + ((u >> 16) & 1u);
    return (u16)(u >> 16);
}

// DPP row-rotate reduction -> halves; finish with readlane(0)+readlane(32).
__device__ inline float rsum_to_halves(float v) {
    int s;
    s = __builtin_bit_cast(int, v);
    v += __builtin_bit_cast(float, __builtin_amdgcn_update_dpp(0, s, 0x121, 0xF, 0xF, false));
    s = __builtin_bit_cast(int, v);
    v += __builtin_bit_cast(float, __builtin_amdgcn_update_dpp(0, s, 0x122, 0xF, 0xF, false));
    s = __builtin_bit_cast(int, v);
    v += __builtin_bit_cast(float, __builtin_amdgcn_update_dpp(0, s, 0x124, 0xF, 0xF, false));
    s = __builtin_bit_cast(int, v);
    v += __builtin_bit_cast(float, __builtin_amdgcn_update_dpp(0, s, 0x128, 0xF, 0xF, false));
    s = __builtin_bit_cast(int, v);
    v += __builtin_bit_cast(float, __builtin_amdgcn_ds_swizzle(s, 0x401F));
    return v;
}

__device__ inline float lane_total(float v) {
    int s = __builtin_bit_cast(int, v);
    return __builtin_bit_cast(float, __builtin_amdgcn_readlane(s, 0)) +
           __builtin_bit_cast(float, __builtin_amdgcn_readlane(s, 32));
}

// ---------------- routing: weights in VGPRs, DPP reduce, fast transcendentals --------
__global__ __launch_bounds__(256, 1) void routing_kernel(
    const float* __restrict__ x, const float* __restrict__ noise,
    const float* __restrict__ w_route, const float* __restrict__ b_route,
    const float* __restrict__ w_noise, const float* __restrict__ b_noise,
    int* __restrict__ top1, float* __restrict__ gate)
{
    int lane = threadIdx.x & 63, w = threadIdx.x >> 6;
    float4 wr4[12], wn4[12];
#pragma unroll
    for (int i = 0; i < 6; ++i) {
        const float4* pr = (const float4*)(w_route + (size_t)(lane + 64 * i) * 8);
        const float4* pn = (const float4*)(w_noise + (size_t)(lane + 64 * i) * 8);
        wr4[2 * i] = pr[0]; wr4[2 * i + 1] = pr[1];
        wn4[2 * i] = pn[0]; wn4[2 * i + 1] = pn[1];
    }
    float br[E_NUM], bn[E_NUM];
#pragma unroll
    for (int e = 0; e < E_NUM; ++e) { br[e] = b_route[e]; bn[e] = b_noise[e]; }

    int tbase = blockIdx.x * 16 + w * 4;
#pragma unroll
    for (int tt = 0; tt < 4; ++tt) {
        int t = tbase + tt;
        const float* xr = x + (size_t)t * CDIM;
        float xv[6];
#pragma unroll
        for (int i = 0; i < 6; ++i) xv[i] = xr[lane + i * 64];
        float ar[E_NUM], an[E_NUM];
#pragma unroll
        for (int e = 0; e < E_NUM; ++e) { ar[e] = 0.f; an[e] = 0.f; }
#pragma unroll
        for (int i = 0; i < 6; ++i) {
            float4 r0 = wr4[2 * i], r1 = wr4[2 * i + 1];
            float4 n0 = wn4[2 * i], n1 = wn4[2 * i + 1];
            float xi = xv[i];
            ar[0] += xi * r0.x; ar[1] += xi * r0.y; ar[2] += xi * r0.z; ar[3] += xi * r0.w;
            ar[4] += xi * r1.x; ar[5] += xi * r1.y; ar[6] += xi * r1.z; ar[7] += xi * r1.w;
            an[0] += xi * n0.x; an[1] += xi * n0.y; an[2] += xi * n0.z; an[3] += xi * n0.w;
            an[4] += xi * n1.x; an[5] += xi * n1.y; an[6] += xi * n1.z; an[7] += xi * n1.w;
        }
        float nz[E_NUM];
        const float* np = noise + (size_t)t * E_NUM;
#pragma unroll
        for (int e = 0; e < E_NUM; ++e) {
            float sr = lane_total(rsum_to_halves(ar[e])) + br[e];
            float sn = lane_total(rsum_to_halves(an[e])) + bn[e];
            float sp = fmaxf(sn, 0.f) + __logf(1.f + __expf(-fabsf(sn)));
            nz[e] = sr + np[e] * sp;
        }
        float v1 = -1e30f; int i1 = 0;
#pragma unroll
        for (int e = 0; e < E_NUM; ++e) if (nz[e] > v1) { v1 = nz[e]; i1 = e; }
        float v2 = -1e30f;
#pragma unroll
        for (int e = 0; e < E_NUM; ++e) if (e != i1 && nz[e] > v2) v2 = nz[e];
        if (lane == 0) {
            gate[t] = 1.f / (1.f + __expf(v2 - v1));
            top1[t] = i1;
        }
    }
}

// ---------------- ballot-aggregated list build + overflow zeroing ----------------
// out memset removed (R7): every token is written by FFN2 exactly once unless its
// expert overflowed cap (statistically never, 68 sigma); dropped rows zeroed here.
__global__ __launch_bounds__(256) void build_lists_kernel(
    const int* __restrict__ top1, int* __restrict__ cnt, int* __restrict__ list,
    float* __restrict__ out)
{
    int t = blockIdx.x * 256 + threadIdx.x;
    int lane = threadIdx.x & 63;
    int e1 = top1[t];
#pragma unroll
    for (int e = 0; e < E_NUM; ++e) {
        unsigned long long m = __ballot(e1 == e);
        if (m == 0) continue;
        int c = __popcll(m);
        int leader = __ffsll((long long)m) - 1;
        int base = 0;
        if (lane == leader) base = atomicAdd(&cnt[e * CNT_PAD], c);
        base = __shfl(base, leader);
        if (e1 == e) {
            int pos = base + __popcll(m & ((1ull << lane) - 1ull));
            if (pos < CAP) {
                list[e * CAP + pos] = t;
            } else {
                float* orow = out + (size_t)t * CDIM;
                for (int i = 0; i < CDIM; ++i) orow[i] = 0.f;
            }
        }
    }
}

// ---------------- packed-row offsets ----------------
__global__ void offsets_kernel(const int* __restrict__ cnt, int* __restrict__ offs)
{
    if (threadIdx.x == 0 && blockIdx.x == 0) {
        int o = 0;
        for (int e = 0; e < E_NUM; ++e) {
            offs[e] = o;
            int n = min(cnt[e * CNT_PAD], CAP);
            o += (n + 127) & ~127;
        }
    }
}

// ------------- transpose + fp32->bf16 convert: in (R,S) -> out (S,R) -------------
__global__ __launch_bounds__(256) void transpose_cvt_kernel(
    const float* __restrict__ in, u16* __restrict__ out, int R, int S)
{
    __shared__ float tile[32][33];
    size_t eoff = (size_t)blockIdx.z * R * S;
    const float* ip = in + eoff;
    u16* op = out + eoff;
    int c0 = blockIdx.x * 32, r0 = blockIdx.y * 32;
    int tx = threadIdx.x, ty = threadIdx.y;
#pragma unroll
    for (int i = ty; i < 32; i += 8)
        tile[i][tx] = ip[(size_t)(r0 + i) * S + (c0 + tx)];
    __syncthreads();
#pragma unroll
    for (int i = ty; i < 32; i += 8)
        op[(size_t)(c0 + i) * R + (r0 + tx)] = f2bf(tile[tx][i]);
}

// ------------- gather x rows -> bf16 into packed layout, zero-pad to 128 -------------
__global__ __launch_bounds__(256) void gather_kernel(
    const float* __restrict__ x, const int* __restrict__ list,
    const int* __restrict__ cnt, const int* __restrict__ offs,
    u16* __restrict__ Xg)
{
    int e = blockIdx.z;
    const int* le = list + (size_t)e * CAP;
    int n = min(cnt[e * CNT_PAD], CAP);
    int w = threadIdx.x >> 6, lane = threadIdx.x & 63;
    int row = blockIdx.x * 4 + w;
    int pad = (n + 127) & ~127;
    if (row >= pad) return;
    u16* orow = Xg + (size_t)(offs[e] + row) * CDIM;
    if (row < n) {
        const float* xr = x + (size_t)le[row] * CDIM;
#pragma unroll
        for (int i = 0; i < CDIM / 64; ++i) orow[lane + i * 64] = f2bf(xr[lane + i * 64]);
    } else {
#pragma unroll
        for (int i = 0; i < CDIM / 64; ++i) orow[lane + i * 64] = 0;
    }
}

// ------------- bf16 MFMA GEMM: 128x128 tile, BK=64, XCD swizzle, XOR bank swizzle,
// R7: G->reg->LDS software pipeline, prefetch distance 2, double-buffered LDS.
// The ds_write of tile k+1 waits (compiler vmcnt) on loads issued a full iter
// earlier; barriers never drain fresh global loads (AITER-style K-loop).
template <int KD, int ND, bool FFN1>
__global__ __launch_bounds__(256, 2) void gemm_kernel(
    const u16* __restrict__ A, const u16* __restrict__ Bt,
    const float* __restrict__ bias, u16* __restrict__ H, float* __restrict__ Out,
    const int* __restrict__ cnt, const int* __restrict__ offs,
    const int* __restrict__ list, const float* __restrict__ gate)
{
    constexpr int NT = ND / 128;
    constexpr int NI = KD / 64;  // 6 (FFN1) or 24 (FFN2), always even
    int bid = blockIdx.x;
    int xcd = bid & 7, slot = bid >> 3;
    int n_idx = slot % NT;
    int mglob = xcd + 8 * (slot / NT);     // 0..511
    int e = mglob >> 6;
    int m0 = (mglob & 63) * 128;
    int n_e = min(cnt[e * CNT_PAD], CAP);
    int pad_e = (n_e + 127) & ~127;
    if (m0 >= pad_e) return;
    int base = offs[e];
    const u16* Ae = A + (size_t)(base + m0) * KD;
    const u16* Be = Bt + ((size_t)e * ND + (size_t)n_idx * 128) * KD;

    __shared__ __align__(16) u16 As[2][128 * 64];
    __shared__ __align__(16) u16 Bs[2][128 * 64];

    int tid = threadIdx.x;
    int w = tid >> 6, lane = tid & 63;
    int quad = lane >> 4, l15 = lane & 15;
    int wr = w & 1, wc = w >> 1;

    int srow = tid >> 3;
    int gcol = ((tid & 7) ^ ((tid >> 3) & 7)) * 8;

    f32x4 acc[4][4];
    f32x4 zero = {0.f, 0.f, 0.f, 0.f};
#pragma unroll
    for (int a = 0; a < 4; ++a)
#pragma unroll
        for (int b = 0; b < 4; ++b) acc[a][b] = zero;

    float4 rA[2][4], rB[2][4];

    auto loadT = [&](int kb, int P) {
#pragma unroll
        for (int i = 0; i < 4; ++i) {
            int row = i * 32 + srow;
            rA[P][i] = *(const float4*)(Ae + (size_t)row * KD + kb * 64 + gcol);
            rB[P][i] = *(const float4*)(Be + (size_t)row * KD + kb * 64 + gcol);
        }
    };
    auto wlds = [&](int P) {
#pragma unroll
        for (int i = 0; i < 4; ++i) {
            *(float4*)&As[P][i * 2048 + tid * 8] = rA[P][i];
            *(float4*)&Bs[P][i * 2048 + tid * 8] = rB[P][i];
        }
    };
    auto compute = [&](int P) {
#pragma unroll
        for (int h = 0; h < 2; ++h) {
            int pga = (((h * 4 + quad) ^ (l15 & 7))) * 8;
            short8 af[4], bf[4];
#pragma unroll
            for (int t = 0; t < 4; ++t) {
                af[t] = *(const short8*)&As[P][(wr * 64 + t * 16 + l15) * 64 + pga];
                bf[t] = *(const short8*)&Bs[P][(wc * 64 + t * 16 + l15) * 64 + pga];
            }
#pragma unroll
            for (int mt = 0; mt < 4; ++mt)
#pragma unroll
                for (int nt = 0; nt < 4; ++nt)
                    acc[mt][nt] = __builtin_amdgcn_mfma_f32_16x16x32_bf16(
                        af[mt], bf[nt], acc[mt][nt], 0, 0, 0);
        }
    };

    // prologue: tile0 -> regs0 -> LDS0; tile1 -> regs1 (in flight)
    loadT(0, 0);
    loadT(1, 1);
    wlds(0);
    __syncthreads();

#pragma unroll 1
    for (int kb = 0; kb < NI; kb += 2) {
        // step P=0: compute tile kb from buf0
        if (kb + 2 < NI) loadT(kb + 2, 0);
        compute(0);
        wlds(1);                       // tile kb+1 (always exists: NI even)
        __syncthreads();
        // step P=1: compute tile kb+1 from buf1
        if (kb + 3 < NI) loadT(kb + 3, 1);
        compute(1);
        if (kb + 2 < NI) {
            wlds(0);                   // tile kb+2
            __syncthreads();
        }
    }

    int n0 = n_idx * 128;
    if (FFN1) {
        u16* He = H + (size_t)(base + m0) * ND;
#pragma unroll
        for (int mt = 0; mt < 4; ++mt) {
            int rowL = wr * 64 + mt * 16 + quad * 4;
#pragma unroll
            for (int nt = 0; nt < 4; ++nt) {
                int col = n0 + wc * 64 + nt * 16 + l15;
                float b = bias[(size_t)e * ND + col];
#pragma unroll
                for (int r = 0; r < 4; ++r) {
                    float v = acc[mt][nt][r] + b;
                    v = fmaxf(v, 0.f);
                    v = v * v;
                    He[(size_t)(rowL + r) * ND + col] = f2bf(v);
                }
            }
        }
    } else {
#pragma unroll
        for (int mt = 0; mt < 4; ++mt) {
            int rowL = wr * 64 + mt * 16 + quad * 4;
#pragma unroll
            for (int r = 0; r < 4; ++r) {
                int rr = m0 + rowL + r;
                if (rr < n_e) {
                    int tok = list[(size_t)e * CAP + rr];
                    float g = gate[tok];
#pragma unroll
                    for (int nt = 0; nt < 4; ++nt) {
                        int col = n0 + wc * 64 + nt * 16 + l15;
                        float v = acc[mt][nt][r] + bias[(size_t)e * ND + col];
                        Out[(size_t)tok * CDIM + col] = v * g;
                    }
                }
            }
        }
    }
}

extern "C" void kernel_launch(void* const* d_in, const int* in_sizes, int n_in,
                              void* d_out, int out_size, void* d_ws, size_t ws_size,
                              hipStream_t stream)
{
    const float* x       = (const float*)d_in[0];
    const float* noise   = (const float*)d_in[1];
    const float* w_route = (const float*)d_in[2];
    const float* b_route = (const float*)d_in[3];
    const float* w_noise = (const float*)d_in[4];
    const float* b_noise = (const float*)d_in[5];
    const float* w1      = (const float*)d_in[6];
    const float* b1      = (const float*)d_in[7];
    const float* w2      = (const float*)d_in[8];
    const float* b2      = (const float*)d_in[9];
    float* out = (float*)d_out;

    char* ws = (char*)d_ws;
    size_t off = 0;
    auto alloc = [&](size_t bytes) {
        char* p = ws + off;
        off += (bytes + 255) & ~(size_t)255;
        return p;
    };
    int*   cnt  = (int*)alloc((size_t)E_NUM * CNT_PAD * sizeof(int));
    int*   top1 = (int*)alloc((size_t)NTOK * sizeof(int));
    int*   list = (int*)alloc((size_t)E_NUM * CAP * sizeof(int));
    float* gate = (float*)alloc((size_t)NTOK * sizeof(float));
    int*   offs = (int*)alloc((size_t)(E_NUM + 1) * sizeof(int));
    u16*   W1t  = (u16*)alloc((size_t)E_NUM * DFF * CDIM * 2);
    u16*   W2t  = (u16*)alloc((size_t)E_NUM * CDIM * DFF * 2);

    size_t rows = NTOK + E_NUM * 128;  // packed-row bound
    u16* Xg = (u16*)alloc(rows * CDIM * 2);
    u16* Hb = (u16*)alloc(rows * DFF * 2);

    hipMemsetAsync(cnt, 0, (size_t)E_NUM * CNT_PAD * sizeof(int), stream);

    routing_kernel<<<NTOK / 16, 256, 0, stream>>>(x, noise, w_route, b_route,
                                                  w_noise, b_noise, top1, gate);
    build_lists_kernel<<<NTOK / 256, 256, 0, stream>>>(top1, cnt, list, out);
    transpose_cvt_kernel<<<dim3(DFF / 32, CDIM / 32, E_NUM), dim3(32, 8), 0, stream>>>(
        w1, W1t, CDIM, DFF);
    transpose_cvt_kernel<<<dim3(CDIM / 32, DFF / 32, E_NUM), dim3(32, 8), 0, stream>>>(
        w2, W2t, DFF, CDIM);
    offsets_kernel<<<1, 64, 0, stream>>>(cnt, offs);
    gather_kernel<<<dim3(CAP / 4, 1, E_NUM), 256, 0, stream>>>(x, list, cnt, offs, Xg);

    gemm_kernel<CDIM, DFF, true><<<dim3((DFF / 128) * 512), 256, 0, stream>>>(
        Xg, W1t, b1, Hb, nullptr, cnt, offs, nullptr, nullptr);
    gemm_kernel<DFF, CDIM, false><<<dim3((CDIM / 128) * 512), 256, 0, stream>>>(
        Hb, W2t, b2, nullptr, out, cnt, offs, list, gate);
}

// Round 8
// 318.498 us; speedup vs baseline: 2.0366x; 2.0366x over previous
//
#include <hip/hip_runtime.h>
#include <stdint.h>

#define E_NUM 8
#define CAP 8192
#define NTOK 32768
#define CDIM 384
#define DFF 1536
#define CNT_PAD 64  // ints between counters -> 256B, separate cache lines

typedef unsigned short u16;
typedef __attribute__((ext_vector_type(8))) short short8;
typedef __attribute__((ext_vector_type(4))) float f32x4;

__device__ inline u16 f2bf(float f) {
    uint32_t u = __builtin_bit_cast(uint32_t, f);
    u += 0x7fffu + ((u >> 16) & 1u);
    return (u16)(u >> 16);
}

__device__ inline void gload_lds16(const void* g, void* l) {
    __builtin_amdgcn_global_load_lds(
        (const __attribute__((address_space(1))) void*)(uintptr_t)g,
        (__attribute__((address_space(3))) void*)(uint32_t)(uintptr_t)l,
        16, 0, 0);
}

// DPP row-rotate reduction -> halves; finish with readlane(0)+readlane(32).
__device__ inline float rsum_to_halves(float v) {
    int s;
    s = __builtin_bit_cast(int, v);
    v += __builtin_bit_cast(float, __builtin_amdgcn_update_dpp(0, s, 0x121, 0xF, 0xF, false));
    s = __builtin_bit_cast(int, v);
    v += __builtin_bit_cast(float, __builtin_amdgcn_update_dpp(0, s, 0x122, 0xF, 0xF, false));
    s = __builtin_bit_cast(int, v);
    v += __builtin_bit_cast(float, __builtin_amdgcn_update_dpp(0, s, 0x124, 0xF, 0xF, false));
    s = __builtin_bit_cast(int, v);
    v += __builtin_bit_cast(float, __builtin_amdgcn_update_dpp(0, s, 0x128, 0xF, 0xF, false));
    s = __builtin_bit_cast(int, v);
    v += __builtin_bit_cast(float, __builtin_amdgcn_ds_swizzle(s, 0x401F));
    return v;
}

__device__ inline float lane_total(float v) {
    int s = __builtin_bit_cast(int, v);
    return __builtin_bit_cast(float, __builtin_amdgcn_readlane(s, 0)) +
           __builtin_bit_cast(float, __builtin_amdgcn_readlane(s, 32));
}

// ---------------- routing: weights in VGPRs, DPP reduce, fast transcendentals --------
__global__ __launch_bounds__(256, 1) void routing_kernel(
    const float* __restrict__ x, const float* __restrict__ noise,
    const float* __restrict__ w_route, const float* __restrict__ b_route,
    const float* __restrict__ w_noise, const float* __restrict__ b_noise,
    int* __restrict__ top1, float* __restrict__ gate)
{
    int lane = threadIdx.x & 63, w = threadIdx.x >> 6;
    float4 wr4[12], wn4[12];
#pragma unroll
    for (int i = 0; i < 6; ++i) {
        const float4* pr = (const float4*)(w_route + (size_t)(lane + 64 * i) * 8);
        const float4* pn = (const float4*)(w_noise + (size_t)(lane + 64 * i) * 8);
        wr4[2 * i] = pr[0]; wr4[2 * i + 1] = pr[1];
        wn4[2 * i] = pn[0]; wn4[2 * i + 1] = pn[1];
    }
    float br[E_NUM], bn[E_NUM];
#pragma unroll
    for (int e = 0; e < E_NUM; ++e) { br[e] = b_route[e]; bn[e] = b_noise[e]; }

    int tbase = blockIdx.x * 16 + w * 4;
#pragma unroll
    for (int tt = 0; tt < 4; ++tt) {
        int t = tbase + tt;
        const float* xr = x + (size_t)t * CDIM;
        float xv[6];
#pragma unroll
        for (int i = 0; i < 6; ++i) xv[i] = xr[lane + i * 64];
        float ar[E_NUM], an[E_NUM];
#pragma unroll
        for (int e = 0; e < E_NUM; ++e) { ar[e] = 0.f; an[e] = 0.f; }
#pragma unroll
        for (int i = 0; i < 6; ++i) {
            float4 r0 = wr4[2 * i], r1 = wr4[2 * i + 1];
            float4 n0 = wn4[2 * i], n1 = wn4[2 * i + 1];
            float xi = xv[i];
            ar[0] += xi * r0.x; ar[1] += xi * r0.y; ar[2] += xi * r0.z; ar[3] += xi * r0.w;
            ar[4] += xi * r1.x; ar[5] += xi * r1.y; ar[6] += xi * r1.z; ar[7] += xi * r1.w;
            an[0] += xi * n0.x; an[1] += xi * n0.y; an[2] += xi * n0.z; an[3] += xi * n0.w;
            an[4] += xi * n1.x; an[5] += xi * n1.y; an[6] += xi * n1.z; an[7] += xi * n1.w;
        }
        float nz[E_NUM];
        const float* np = noise + (size_t)t * E_NUM;
#pragma unroll
        for (int e = 0; e < E_NUM; ++e) {
            float sr = lane_total(rsum_to_halves(ar[e])) + br[e];
            float sn = lane_total(rsum_to_halves(an[e])) + bn[e];
            float sp = fmaxf(sn, 0.f) + __logf(1.f + __expf(-fabsf(sn)));
            nz[e] = sr + np[e] * sp;
        }
        float v1 = -1e30f; int i1 = 0;
#pragma unroll
        for (int e = 0; e < E_NUM; ++e) if (nz[e] > v1) { v1 = nz[e]; i1 = e; }
        float v2 = -1e30f;
#pragma unroll
        for (int e = 0; e < E_NUM; ++e) if (e != i1 && nz[e] > v2) v2 = nz[e];
        if (lane == 0) {
            gate[t] = 1.f / (1.f + __expf(v2 - v1));
            top1[t] = i1;
        }
    }
}

// ---------------- ballot-aggregated list build + overflow zeroing ----------------
__global__ __launch_bounds__(256) void build_lists_kernel(
    const int* __restrict__ top1, int* __restrict__ cnt, int* __restrict__ list,
    float* __restrict__ out)
{
    int t = blockIdx.x * 256 + threadIdx.x;
    int lane = threadIdx.x & 63;
    int e1 = top1[t];
#pragma unroll
    for (int e = 0; e < E_NUM; ++e) {
        unsigned long long m = __ballot(e1 == e);
        if (m == 0) continue;
        int c = __popcll(m);
        int leader = __ffsll((long long)m) - 1;
        int base = 0;
        if (lane == leader) base = atomicAdd(&cnt[e * CNT_PAD], c);
        base = __shfl(base, leader);
        if (e1 == e) {
            int pos = base + __popcll(m & ((1ull << lane) - 1ull));
            if (pos < CAP) {
                list[e * CAP + pos] = t;
            } else {
                float* orow = out + (size_t)t * CDIM;
                for (int i = 0; i < CDIM; ++i) orow[i] = 0.f;
            }
        }
    }
}

// ---------------- packed-row offsets ----------------
__global__ void offsets_kernel(const int* __restrict__ cnt, int* __restrict__ offs)
{
    if (threadIdx.x == 0 && blockIdx.x == 0) {
        int o = 0;
        for (int e = 0; e < E_NUM; ++e) {
            offs[e] = o;
            int n = min(cnt[e * CNT_PAD], CAP);
            o += (n + 127) & ~127;
        }
    }
}

// ------------- transpose + fp32->bf16 convert: in (R,S) -> out (S,R) -------------
__global__ __launch_bounds__(256) void transpose_cvt_kernel(
    const float* __restrict__ in, u16* __restrict__ out, int R, int S)
{
    __shared__ float tile[32][33];
    size_t eoff = (size_t)blockIdx.z * R * S;
    const float* ip = in + eoff;
    u16* op = out + eoff;
    int c0 = blockIdx.x * 32, r0 = blockIdx.y * 32;
    int tx = threadIdx.x, ty = threadIdx.y;
#pragma unroll
    for (int i = ty; i < 32; i += 8)
        tile[i][tx] = ip[(size_t)(r0 + i) * S + (c0 + tx)];
    __syncthreads();
#pragma unroll
    for (int i = ty; i < 32; i += 8)
        op[(size_t)(c0 + i) * R + (r0 + tx)] = f2bf(tile[tx][i]);
}

// ------------- gather x rows -> bf16 into packed layout, zero-pad to 128 -------------
__global__ __launch_bounds__(256) void gather_kernel(
    const float* __restrict__ x, const int* __restrict__ list,
    const int* __restrict__ cnt, const int* __restrict__ offs,
    u16* __restrict__ Xg)
{
    int e = blockIdx.z;
    const int* le = list + (size_t)e * CAP;
    int n = min(cnt[e * CNT_PAD], CAP);
    int w = threadIdx.x >> 6, lane = threadIdx.x & 63;
    int row = blockIdx.x * 4 + w;
    int pad = (n + 127) & ~127;
    if (row >= pad) return;
    u16* orow = Xg + (size_t)(offs[e] + row) * CDIM;
    if (row < n) {
        const float* xr = x + (size_t)le[row] * CDIM;
#pragma unroll
        for (int i = 0; i < CDIM / 64; ++i) orow[lane + i * 64] = f2bf(xr[lane + i * 64]);
    } else {
#pragma unroll
        for (int i = 0; i < CDIM / 64; ++i) orow[lane + i * 64] = 0;
    }
}

// ------------- bf16 MFMA GEMM: 128x128 tile, BK=64, XCD swizzle, XOR bank swizzle.
// R8: double-buffered LDS fed by global_load_lds DMA (zero VGPR cost — R7's
// register pipeline spilled to scratch: WRITE_SIZE 49->613MB). DMA for tile k+1
// issues before compute of tile k; the single barrier per iter drains only the
// latency remainder. Buffer index is compile-time via 2x unroll.
template <int KD, int ND, bool FFN1>
__global__ __launch_bounds__(256, 2) void gemm_kernel(
    const u16* __restrict__ A, const u16* __restrict__ Bt,
    const float* __restrict__ bias, u16* __restrict__ H, float* __restrict__ Out,
    const int* __restrict__ cnt, const int* __restrict__ offs,
    const int* __restrict__ list, const float* __restrict__ gate)
{
    constexpr int NT = ND / 128;
    constexpr int NI = KD / 64;  // 6 (FFN1) or 24 (FFN2), always even
    int bid = blockIdx.x;
    int xcd = bid & 7, slot = bid >> 3;
    int n_idx = slot % NT;
    int mglob = xcd + 8 * (slot / NT);     // 0..511
    int e = mglob >> 6;
    int m0 = (mglob & 63) * 128;
    int n_e = min(cnt[e * CNT_PAD], CAP);
    int pad_e = (n_e + 127) & ~127;
    if (m0 >= pad_e) return;
    int base = offs[e];
    const u16* Ae = A + (size_t)(base + m0) * KD;
    const u16* Be = Bt + ((size_t)e * ND + (size_t)n_idx * 128) * KD;

    __shared__ __align__(16) u16 As[2][128 * 64];
    __shared__ __align__(16) u16 Bs[2][128 * 64];

    int tid = threadIdx.x;
    int w = tid >> 6, lane = tid & 63;
    int quad = lane >> 4, l15 = lane & 15;
    int wr = w & 1, wc = w >> 1;

    int srow = tid >> 3;
    int gcol = ((tid & 7) ^ ((tid >> 3) & 7)) * 8;

    f32x4 acc[4][4];
    f32x4 zero = {0.f, 0.f, 0.f, 0.f};
#pragma unroll
    for (int a = 0; a < 4; ++a)
#pragma unroll
        for (int b = 0; b < 4; ++b) acc[a][b] = zero;

    auto stage = [&](int kb, int P) {
#pragma unroll
        for (int i = 0; i < 4; ++i) {
            int row = i * 32 + srow;
            gload_lds16(Ae + (size_t)row * KD + kb * 64 + gcol, &As[P][i * 2048 + tid * 8]);
            gload_lds16(Be + (size_t)row * KD + kb * 64 + gcol, &Bs[P][i * 2048 + tid * 8]);
        }
    };
    auto compute = [&](int P) {
#pragma unroll
        for (int h = 0; h < 2; ++h) {
            int pga = (((h * 4 + quad) ^ (l15 & 7))) * 8;
            short8 af[4], bf[4];
#pragma unroll
            for (int t = 0; t < 4; ++t) {
                af[t] = *(const short8*)&As[P][(wr * 64 + t * 16 + l15) * 64 + pga];
                bf[t] = *(const short8*)&Bs[P][(wc * 64 + t * 16 + l15) * 64 + pga];
            }
#pragma unroll
            for (int mt = 0; mt < 4; ++mt)
#pragma unroll
                for (int nt = 0; nt < 4; ++nt)
                    acc[mt][nt] = __builtin_amdgcn_mfma_f32_16x16x32_bf16(
                        af[mt], bf[nt], acc[mt][nt], 0, 0, 0);
        }
    };

    stage(0, 0);
    __syncthreads();              // tile0 resident

#pragma unroll 1
    for (int kb = 0; kb < NI; kb += 2) {
        stage(kb + 1, 1);         // DMA tile kb+1 while computing kb (NI even -> exists)
        compute(0);
        __syncthreads();          // drains stage(kb+1) remainder
        if (kb + 2 < NI) stage(kb + 2, 0);
        compute(1);
        __syncthreads();          // drains stage(kb+2); buf1 safe to rewrite next iter
    }

    int n0 = n_idx * 128;
    if (FFN1) {
        u16* He = H + (size_t)(base + m0) * ND;
#pragma unroll
        for (int mt = 0; mt < 4; ++mt) {
            int rowL = wr * 64 + mt * 16 + quad * 4;
#pragma unroll
            for (int nt = 0; nt < 4; ++nt) {
                int col = n0 + wc * 64 + nt * 16 + l15;
                float b = bias[(size_t)e * ND + col];
#pragma unroll
                for (int r = 0; r < 4; ++r) {
                    float v = acc[mt][nt][r] + b;
                    v = fmaxf(v, 0.f);
                    v = v * v;
                    He[(size_t)(rowL + r) * ND + col] = f2bf(v);
                }
            }
        }
    } else {
#pragma unroll
        for (int mt = 0; mt < 4; ++mt) {
            int rowL = wr * 64 + mt * 16 + quad * 4;
#pragma unroll
            for (int r = 0; r < 4; ++r) {
                int rr = m0 + rowL + r;
                if (rr < n_e) {
                    int tok = list[(size_t)e * CAP + rr];
                    float g = gate[tok];
#pragma unroll
                    for (int nt = 0; nt < 4; ++nt) {
                        int col = n0 + wc * 64 + nt * 16 + l15;
                        float v = acc[mt][nt][r] + bias[(size_t)e * ND + col];
                        Out[(size_t)tok * CDIM + col] = v * g;
                    }
                }
            }
        }
    }
}

extern "C" void kernel_launch(void* const* d_in, const int* in_sizes, int n_in,
                              void* d_out, int out_size, void* d_ws, size_t ws_size,
                              hipStream_t stream)
{
    const float* x       = (const float*)d_in[0];
    const float* noise   = (const float*)d_in[1];
    const float* w_route = (const float*)d_in[2];
    const float* b_route = (const float*)d_in[3];
    const float* w_noise = (const float*)d_in[4];
    const float* b_noise = (const float*)d_in[5];
    const float* w1      = (const float*)d_in[6];
    const float* b1      = (const float*)d_in[7];
    const float* w2      = (const float*)d_in[8];
    const float* b2      = (const float*)d_in[9];
    float* out = (float*)d_out;

    char* ws = (char*)d_ws;
    size_t off = 0;
    auto alloc = [&](size_t bytes) {
        char* p = ws + off;
        off += (bytes + 255) & ~(size_t)255;
        return p;
    };
    int*   cnt  = (int*)alloc((size_t)E_NUM * CNT_PAD * sizeof(int));
    int*   top1 = (int*)alloc((size_t)NTOK * sizeof(int));
    int*   list = (int*)alloc((size_t)E_NUM * CAP * sizeof(int));
    float* gate = (float*)alloc((size_t)NTOK * sizeof(float));
    int*   offs = (int*)alloc((size_t)(E_NUM + 1) * sizeof(int));
    u16*   W1t  = (u16*)alloc((size_t)E_NUM * DFF * CDIM * 2);
    u16*   W2t  = (u16*)alloc((size_t)E_NUM * CDIM * DFF * 2);

    size_t rows = NTOK + E_NUM * 128;  // packed-row bound
    u16* Xg = (u16*)alloc(rows * CDIM * 2);
    u16* Hb = (u16*)alloc(rows * DFF * 2);

    hipMemsetAsync(cnt, 0, (size_t)E_NUM * CNT_PAD * sizeof(int), stream);

    routing_kernel<<<NTOK / 16, 256, 0, stream>>>(x, noise, w_route, b_route,
                                                  w_noise, b_noise, top1, gate);
    build_lists_kernel<<<NTOK / 256, 256, 0, stream>>>(top1, cnt, list, out);
    transpose_cvt_kernel<<<dim3(DFF / 32, CDIM / 32, E_NUM), dim3(32, 8), 0, stream>>>(
        w1, W1t, CDIM, DFF);
    transpose_cvt_kernel<<<dim3(CDIM / 32, DFF / 32, E_NUM), dim3(32, 8), 0, stream>>>(
        w2, W2t, DFF, CDIM);
    offsets_kernel<<<1, 64, 0, stream>>>(cnt, offs);
    gather_kernel<<<dim3(CAP / 4, 1, E_NUM), 256, 0, stream>>>(x, list, cnt, offs, Xg);

    gemm_kernel<CDIM, DFF, true><<<dim3((DFF / 128) * 512), 256, 0, stream>>>(
        Xg, W1t, b1, Hb, nullptr, cnt, offs, nullptr, nullptr);
    gemm_kernel<DFF, CDIM, false><<<dim3((CDIM / 128) * 512), 256, 0, stream>>>(
        Hb, W2t, b2, nullptr, out, cnt, offs, list, gate);
}